// Round 14
// baseline (128.729 us; speedup 1.0000x reference)
//
#include <hip/hip_runtime.h>
#include <hip/hip_bf16.h>

// SubjectLayers: out[b,t,o] = sum_i x[b,t,i] * w[sid[b],i,o] + bias[sid[b],o]
// B=256 T=512 IN=256 OUT=256 S=128, all fp32 in/out.
// R14: B-IN-REGISTERS design. One block per batch (grid=256, 1 block/CU).
// Each wave holds its 32-col x full-K B-slice in 64 VGPRs (loaded ONCE:
// B issued = 33.5 MB, the unique-byte floor). Block loops over the batch's
// four 128-row A-tiles: stage to LDS (verified swizzle), then a K-loop that
// is PURE LDS+MFMA (zero VMEM dependency - first round with this property).
// Tile at+1's A-loads issue under K-loop(at); stores drain under next stage.
// Issued total = A 134 + B 34 + stores 134 = 302 MB.

#define B_DIM 256
#define T_DIM 512
#define IN_DIM 256
#define OUT_DIM 256
#define S_DIM 128

typedef __attribute__((ext_vector_type(4))) float f32x4;
typedef __attribute__((ext_vector_type(8))) short s16x8;
typedef __attribute__((ext_vector_type(8))) unsigned short u16x8;
typedef __attribute__((ext_vector_type(4))) unsigned short u16x4;

static __device__ __forceinline__ unsigned short f2bf(float f) {
  __hip_bfloat16 h = __float2bfloat16(f);
  return __builtin_bit_cast(unsigned short, h);
}

// Pre-pass: chunk-major transposed weights (identical to R10-R13).
// wT2 element (s, o, i) at ((s*32 + (i>>3))*256 + o)*8 + (i&7).
__global__ __launch_bounds__(256) void wt_transpose(const float* __restrict__ w,
                                                    unsigned short* __restrict__ wT2) {
  __shared__ float tile[64][65];
  int bid = blockIdx.x;
  int s = bid >> 4, ti = (bid >> 2) & 3, to = bid & 3;
  const float* wp = w + (size_t)s * IN_DIM * OUT_DIM;
  int t = threadIdx.x;
  int rr = t >> 6, cc = t & 63;
#pragma unroll
  for (int p = 0; p < 16; ++p) {
    tile[p * 4 + rr][cc] = wp[(size_t)(ti * 64 + p * 4 + rr) * OUT_DIM + to * 64 + cc];
  }
  __syncthreads();
  int orr = t >> 4, i4 = (t & 15) * 4;
#pragma unroll
  for (int p = 0; p < 4; ++p) {
    int ol = p * 16 + orr;        // o within 64-tile
    int i0 = ti * 64 + i4;        // global i of first of 4
    u16x4 v;
    v[0] = f2bf(tile[i4 + 0][ol]);
    v[1] = f2bf(tile[i4 + 1][ol]);
    v[2] = f2bf(tile[i4 + 2][ol]);
    v[3] = f2bf(tile[i4 + 3][ol]);
    size_t idx = ((size_t)(s * 32 + (i0 >> 3)) * OUT_DIM + (to * 64 + ol)) * 8 + (i0 & 7);
    *(u16x4*)(wT2 + idx) = v;
  }
}

// Block = one batch (512 rows x 256 cols), 512 threads = 8 waves.
// Wave = 128 rows x its own 32-col slice per tile (8fm x 2fn frags).
// B: wave's full-K 32-col slice in registers breg[2][8] (16 x s16x8).
// A LDS (bf16, 64KB): row r = 512B; chunk c (16B) at r*512 + ((c^(r&15))<<4).
__global__ __launch_bounds__(512) void subj_gemm_v14(
    const float* __restrict__ x, const int* __restrict__ sid,
    const unsigned short* __restrict__ wT2, const float* __restrict__ bias,
    float* __restrict__ out) {
  __shared__ __align__(16) unsigned short lA[128 * IN_DIM];  // 64 KB

  // XCD chunking: 256 blocks -> 32 consecutive batches per XCD
  unsigned wg = blockIdx.x;
  int batch = (int)((wg & 7u) * 32u + (wg >> 3));
  int s = sid[batch];

  int t = threadIdx.x;
  int l = t & 63, wv = t >> 6;
  int wn = wv * 32;               // wave's 32-col slice
  int fr = l & 15, kq = l >> 4;
  int r0 = kq * 4;                // C/D row group

  const float* xb = x + (size_t)batch * T_DIM * IN_DIM;
  const unsigned short* wbase = wT2 + (size_t)s * 32 * OUT_DIM * 8;

  // ---- B: load wave's full-K slice into registers (16 loads, once).
  s16x8 breg[2][8];
#pragma unroll
  for (int stp = 0; stp < 8; ++stp)
#pragma unroll
    for (int fn = 0; fn < 2; ++fn)
      breg[fn][stp] = *(const s16x8*)(wbase +
                                      ((size_t)(stp * 4 + kq) * OUT_DIM + wn +
                                       fn * 16 + fr) * 8);

  // bias (same for all tiles)
  const float* bp = bias + (size_t)s * OUT_DIM + wn;
  float bv[2];
#pragma unroll
  for (int fn = 0; fn < 2; ++fn) bv[fn] = bp[fn * 16 + fr];

  // ---- A staging regs: 16 f32x4 (256B/thread of the 128KB tile)
  f32x4 aR[16];
#define ISSUE_A(at)                                                           \
  do {                                                                        \
    const float* xt = xb + (size_t)(at) * 128 * IN_DIM;                       \
    _Pragma("unroll") for (int j = 0; j < 4; ++j)                             \
      _Pragma("unroll") for (int p = 0; p < 4; ++p)                           \
        aR[j * 4 + p] = *(const f32x4*)(xt + (size_t)j * 8192 + t * 16 + p * 4); \
  } while (0)
#define CVT_WRITE()                                                           \
  do {                                                                        \
    _Pragma("unroll") for (int j = 0; j < 4; ++j)                             \
      _Pragma("unroll") for (int h = 0; h < 2; ++h) {                         \
        int cf = j * 1024 + 2 * t + h;                                        \
        int row = cf >> 5, c = cf & 31;                                       \
        u16x8 v;                                                              \
        v[0] = f2bf(aR[j * 4 + 2 * h][0]); v[1] = f2bf(aR[j * 4 + 2 * h][1]); \
        v[2] = f2bf(aR[j * 4 + 2 * h][2]); v[3] = f2bf(aR[j * 4 + 2 * h][3]); \
        v[4] = f2bf(aR[j * 4 + 2 * h + 1][0]);                                \
        v[5] = f2bf(aR[j * 4 + 2 * h + 1][1]);                                \
        v[6] = f2bf(aR[j * 4 + 2 * h + 1][2]);                                \
        v[7] = f2bf(aR[j * 4 + 2 * h + 1][3]);                                \
        *(u16x8*)((unsigned char*)&lA[0] + row * 512 +                        \
                  ((c ^ (row & 15)) << 4)) = v;                               \
      }                                                                       \
  } while (0)

  ISSUE_A(0);

  // ---- loop over the batch's four 128-row tiles
#pragma unroll
  for (int at = 0; at < 4; ++at) {
    // aR for tile `at` ready (16 newest loads; older stores may linger)
    if (at == 0) asm volatile("s_waitcnt vmcnt(0)");
    else         asm volatile("s_waitcnt vmcnt(63)");  // 64 stores newest; drain loads
    __builtin_amdgcn_sched_barrier(0);
    CVT_WRITE();
    if (at < 3) ISSUE_A(at + 1);   // next tile's HBM reads fly under K-loop
    asm volatile("s_waitcnt lgkmcnt(0)");
    __builtin_amdgcn_sched_barrier(0);
    __syncthreads();               // lA(at) visible to all waves

    f32x4 acc[8][2];
#pragma unroll
    for (int i = 0; i < 8; ++i)
#pragma unroll
      for (int j = 0; j < 2; ++j) acc[i][j] = (f32x4){0.f, 0.f, 0.f, 0.f};

    // pure LDS+MFMA K-loop: 8 steps x (8 ds_read_b128 + 16 MFMA)
#pragma unroll
    for (int stp = 0; stp < 8; ++stp) {
      s16x8 af[8];
#pragma unroll
      for (int fm = 0; fm < 8; ++fm) {
        int row = fm * 16 + fr;
        unsigned c = (unsigned)(stp * 4) + (unsigned)kq;
        af[fm] = *(const s16x8*)((const unsigned char*)&lA[0] + row * 512 +
                                 ((c ^ (unsigned)(row & 15)) << 4));
      }
#pragma unroll
      for (int fm = 0; fm < 8; ++fm)
#pragma unroll
        for (int fn = 0; fn < 2; ++fn)
          acc[fm][fn] = __builtin_amdgcn_mfma_f32_16x16x32_bf16(
              af[fm], breg[fn][stp], acc[fm][fn], 0, 0, 0);
    }

    __syncthreads();               // all waves done reading lA(at)

    // stores for tile `at` (drain under next tile's stage)
    float* orow = out + ((size_t)batch * T_DIM + at * 128) * OUT_DIM + wn;
#pragma unroll
    for (int fm = 0; fm < 8; ++fm)
#pragma unroll
      for (int r = 0; r < 4; ++r)
#pragma unroll
        for (int fn = 0; fn < 2; ++fn)
          orow[(size_t)(fm * 16 + r0 + r) * OUT_DIM + fn * 16 + fr] =
              acc[fm][fn][r] + bv[fn];
  }
#undef ISSUE_A
#undef CVT_WRITE
}

// Emergency fallback if d_ws is too small: correct but slow.
__global__ __launch_bounds__(256) void naive_kernel(
    const float* __restrict__ x, const int* __restrict__ sid,
    const float* __restrict__ w, const float* __restrict__ bias,
    float* __restrict__ out) {
  __shared__ float lx[IN_DIM];
  size_t bt = blockIdx.x;
  int batch = (int)(bt / T_DIM);
  int s = sid[batch];
  int o = threadIdx.x;
  lx[o] = x[bt * IN_DIM + o];
  __syncthreads();
  const float* wp = w + (size_t)s * IN_DIM * OUT_DIM + o;
  float acc = bias[(size_t)s * OUT_DIM + o];
  for (int i = 0; i < IN_DIM; ++i) acc += lx[i] * wp[(size_t)i * OUT_DIM];
  out[bt * OUT_DIM + o] = acc;
}

extern "C" void kernel_launch(void* const* d_in, const int* in_sizes, int n_in,
                              void* d_out, int out_size, void* d_ws, size_t ws_size,
                              hipStream_t stream) {
  const float* x = (const float*)d_in[0];
  const int* sid = (const int*)d_in[1];
  const float* w = (const float*)d_in[2];
  const float* bias = (const float*)d_in[3];
  float* out = (float*)d_out;

  size_t need = (size_t)S_DIM * IN_DIM * OUT_DIM * sizeof(unsigned short);
  if (ws_size >= need) {
    unsigned short* wT2 = (unsigned short*)d_ws;
    wt_transpose<<<dim3(S_DIM * 16), dim3(256), 0, stream>>>(w, wT2);
    subj_gemm_v14<<<dim3(256), dim3(512), 0, stream>>>(x, sid, wT2, bias, out);
  } else {
    naive_kernel<<<dim3(B_DIM * T_DIM), dim3(256), 0, stream>>>(x, sid, w, bias, out);
  }
}

// Round 15
// 79.515 us; speedup vs baseline: 1.6189x; 1.6189x over previous
//
#include <hip/hip_runtime.h>
#include <hip/hip_bf16.h>

// SubjectLayers: out[b,t,o] = sum_i x[b,t,i] * w[sid[b],i,o] + bias[sid[b],o]
// B=256 T=512 IN=256 OUT=256 S=128, all fp32 in/out.
// R15 = R11 (measured best, 79.1 us) + A-staging bank-conflict fix.
// R11 structure: A staged once per 64-row block (bf16 LDS, 1 barrier total),
// B direct-to-register from chunk-major wT2 (L2-hot, 2-deep ping-pong, NO
// barriers in K-loop), 32KB LDS -> 3 blocks/CU overlap staging bursts.
// Fix: thread->chunk map cf=j*256+t (consecutive lanes -> consecutive 16B
// chunks) turns the 4-way A-write conflict (524K) into free 2-way.

#define B_DIM 256
#define T_DIM 512
#define IN_DIM 256
#define OUT_DIM 256
#define S_DIM 128

typedef __attribute__((ext_vector_type(4))) float f32x4;
typedef __attribute__((ext_vector_type(8))) short s16x8;
typedef __attribute__((ext_vector_type(8))) unsigned short u16x8;
typedef __attribute__((ext_vector_type(4))) unsigned short u16x4;

static __device__ __forceinline__ unsigned short f2bf(float f) {
  __hip_bfloat16 h = __float2bfloat16(f);
  return __builtin_bit_cast(unsigned short, h);
}

// Pre-pass: chunk-major transposed weights (identical to R10/R11).
// wT2 element (s, o, i) at ((s*32 + (i>>3))*256 + o)*8 + (i&7).
__global__ __launch_bounds__(256) void wt_transpose(const float* __restrict__ w,
                                                    unsigned short* __restrict__ wT2) {
  __shared__ float tile[64][65];
  int bid = blockIdx.x;
  int s = bid >> 4, ti = (bid >> 2) & 3, to = bid & 3;
  const float* wp = w + (size_t)s * IN_DIM * OUT_DIM;
  int t = threadIdx.x;
  int rr = t >> 6, cc = t & 63;
#pragma unroll
  for (int p = 0; p < 16; ++p) {
    tile[p * 4 + rr][cc] = wp[(size_t)(ti * 64 + p * 4 + rr) * OUT_DIM + to * 64 + cc];
  }
  __syncthreads();
  int orr = t >> 4, i4 = (t & 15) * 4;
#pragma unroll
  for (int p = 0; p < 4; ++p) {
    int ol = p * 16 + orr;        // o within 64-tile
    int i0 = ti * 64 + i4;        // global i of first of 4
    u16x4 v;
    v[0] = f2bf(tile[i4 + 0][ol]);
    v[1] = f2bf(tile[i4 + 1][ol]);
    v[2] = f2bf(tile[i4 + 2][ol]);
    v[3] = f2bf(tile[i4 + 3][ol]);
    size_t idx = ((size_t)(s * 32 + (i0 >> 3)) * OUT_DIM + (to * 64 + ol)) * 8 + (i0 & 7);
    *(u16x4*)(wT2 + idx) = v;
  }
}

// Block = 64 T-rows x 256 O-cols, 256 threads = 4 waves, wave = 64 rows x
// 64 cols (4fm x 4fn frags of 16x16x32 bf16 MFMA). 8 K-steps of 32.
// A LDS (bf16, 32KB, staged once): row r = 512B; chunk c (16B) at byte
//   r*512 + ((c ^ (r&15))<<4)   [verified 0-conflict on reads]
// B: DIRECT global->reg, 2-deep named ping-pong, no barriers.
__global__ __launch_bounds__(256) void subj_gemm_v15(
    const float* __restrict__ x, const int* __restrict__ sid,
    const unsigned short* __restrict__ wT2, const float* __restrict__ bias,
    float* __restrict__ out) {
  __shared__ __align__(16) unsigned short lA[64 * IN_DIM];  // 32 KB

  // bijective XCD chunking: 256 consecutive bids per XCD (32 whole batches)
  unsigned wg = blockIdx.x;
  unsigned bid = (wg & 7u) * 256u + (wg >> 3);
  int batch = bid >> 3;
  int rb = bid & 7;  // 64-row segment
  int s = sid[batch];

  int t = threadIdx.x;
  int l = t & 63, wv = t >> 6;
  int wn = wv * 64;               // wave's 64-col slice; all waves share rows
  int fr = l & 15, kq = l >> 4;
  int r0 = kq * 4;                // C/D row group

  const float* xbase = x + ((size_t)batch * T_DIM + rb * 64) * IN_DIM;  // 64KB
  const unsigned short* wbase = wT2 + (size_t)s * 32 * OUT_DIM * 8;

  // ---- B fragment loader: k-chunk stp*4+kq, cols wn+fn*16+fr; 16B contiguous
#define LOADB(dst, stp)                                                       \
  do {                                                                        \
    _Pragma("unroll") for (int fn = 0; fn < 4; ++fn)                          \
        dst[fn] = *(const s16x8*)(wbase +                                     \
                                  ((size_t)((stp) * 4 + kq) * OUT_DIM + wn +  \
                                   fn * 16 + fr) * 8);                        \
  } while (0)

  // ---- issue first B tile immediately (L2 latency hides under A staging)
  s16x8 bA[4], bB[4];
  LOADB(bA, 0);

  // ---- A staging: thread t handles chunks cf = j*256 + t (j=0..7):
  // row = cf>>5, cc = cf&31; f32 src = xbase + row*256 + cc*8 (+4).
  // Consecutive lanes -> consecutive chunks: writes 2-way aliased (free),
  // reads 1KB/32-lane contiguous.
  {
    f32x4 aR[8][2];
#pragma unroll
    for (int j = 0; j < 8; ++j) {
      int cf = j * 256 + t;
      int row = cf >> 5, cc = cf & 31;
      const float* src = xbase + (size_t)row * IN_DIM + cc * 8;
      aR[j][0] = *(const f32x4*)src;
      aR[j][1] = *(const f32x4*)(src + 4);
    }
#pragma unroll
    for (int j = 0; j < 8; ++j) {
      int cf = j * 256 + t;
      int row = cf >> 5, cc = cf & 31;
      u16x8 v;
      v[0] = f2bf(aR[j][0][0]); v[1] = f2bf(aR[j][0][1]);
      v[2] = f2bf(aR[j][0][2]); v[3] = f2bf(aR[j][0][3]);
      v[4] = f2bf(aR[j][1][0]); v[5] = f2bf(aR[j][1][1]);
      v[6] = f2bf(aR[j][1][2]); v[7] = f2bf(aR[j][1][3]);
      *(u16x8*)((unsigned char*)&lA[0] + row * 512 + ((cc ^ (row & 15)) << 4)) = v;
    }
  }
  __syncthreads();  // the ONLY barrier: A staged for all waves

  f32x4 acc[4][4];
#pragma unroll
  for (int i = 0; i < 4; ++i)
#pragma unroll
    for (int j = 0; j < 4; ++j) acc[i][j] = (f32x4){0.f, 0.f, 0.f, 0.f};

  // ---- barrier-free K-loop: 8 steps, B 2-deep ping-pong, A from LDS.
#define AFRAG(dst, stp)                                                       \
  do {                                                                        \
    _Pragma("unroll") for (int fm = 0; fm < 4; ++fm) {                        \
      int row = fm * 16 + fr;                                                 \
      unsigned c = (unsigned)((stp) * 4 + kq);                                \
      dst[fm] = *(const s16x8*)((const unsigned char*)&lA[0] + row * 512 +    \
                                ((c ^ (unsigned)(row & 15)) << 4));           \
    }                                                                         \
  } while (0)
#define MFMA_STEP(breg)                                                       \
  do {                                                                        \
    _Pragma("unroll") for (int fm = 0; fm < 4; ++fm)                          \
      _Pragma("unroll") for (int fn = 0; fn < 4; ++fn)                        \
          acc[fm][fn] = __builtin_amdgcn_mfma_f32_16x16x32_bf16(              \
              af[fm], breg[fn], acc[fm][fn], 0, 0, 0);                        \
  } while (0)

  s16x8 af[4];
#pragma unroll
  for (int sp = 0; sp < 8; sp += 2) {
    LOADB(bB, sp + 1);          // next B in flight during this step's MFMAs
    AFRAG(af, sp);
    MFMA_STEP(bA);
    if (sp + 2 < 8) LOADB(bA, sp + 2);
    AFRAG(af, sp + 1);
    MFMA_STEP(bB);
  }

  // ---- epilogue: bias + store (16-lane groups, 64B contiguous per fn)
  const float* bp = bias + (size_t)s * OUT_DIM + wn;
  float bv[4];
#pragma unroll
  for (int fn = 0; fn < 4; ++fn) bv[fn] = bp[fn * 16 + fr];

  float* orow = out + ((size_t)batch * T_DIM + rb * 64) * OUT_DIM + wn;
#pragma unroll
  for (int fm = 0; fm < 4; ++fm)
#pragma unroll
    for (int r = 0; r < 4; ++r)
#pragma unroll
      for (int fn = 0; fn < 4; ++fn)
        orow[(size_t)(fm * 16 + r0 + r) * OUT_DIM + fn * 16 + fr] =
            acc[fm][fn][r] + bv[fn];
#undef LOADB
#undef AFRAG
#undef MFMA_STEP
}

// Emergency fallback if d_ws is too small: correct but slow.
__global__ __launch_bounds__(256) void naive_kernel(
    const float* __restrict__ x, const int* __restrict__ sid,
    const float* __restrict__ w, const float* __restrict__ bias,
    float* __restrict__ out) {
  __shared__ float lx[IN_DIM];
  size_t bt = blockIdx.x;
  int batch = (int)(bt / T_DIM);
  int s = sid[batch];
  int o = threadIdx.x;
  lx[o] = x[bt * IN_DIM + o];
  __syncthreads();
  const float* wp = w + (size_t)s * IN_DIM * OUT_DIM + o;
  float acc = bias[(size_t)s * OUT_DIM + o];
  for (int i = 0; i < IN_DIM; ++i) acc += lx[i] * wp[(size_t)i * OUT_DIM];
  out[bt * OUT_DIM + o] = acc;
}

extern "C" void kernel_launch(void* const* d_in, const int* in_sizes, int n_in,
                              void* d_out, int out_size, void* d_ws, size_t ws_size,
                              hipStream_t stream) {
  const float* x = (const float*)d_in[0];
  const int* sid = (const int*)d_in[1];
  const float* w = (const float*)d_in[2];
  const float* bias = (const float*)d_in[3];
  float* out = (float*)d_out;

  size_t need = (size_t)S_DIM * IN_DIM * OUT_DIM * sizeof(unsigned short);
  if (ws_size >= need) {
    unsigned short* wT2 = (unsigned short*)d_ws;
    wt_transpose<<<dim3(S_DIM * 16), dim3(256), 0, stream>>>(w, wT2);
    subj_gemm_v15<<<dim3(2048), dim3(256), 0, stream>>>(x, sid, wT2, bias, out);
  } else {
    naive_kernel<<<dim3(B_DIM * T_DIM), dim3(256), 0, stream>>>(x, sid, w, bias, out);
  }
}